// Round 7
// baseline (410.230 us; speedup 1.0000x reference)
//
#include <hip/hip_runtime.h>
#include <hip/hip_bf16.h>

#define T_DIM 2048
#define C_DIM 1024
#define NHEAD 16
#define DHEAD 64

typedef __attribute__((ext_vector_type(8))) short s16x8;   // 8 bf16 = 4 VGPRs
typedef __attribute__((ext_vector_type(4))) short s16x4;   // 4 bf16 = 2 VGPRs
typedef __attribute__((ext_vector_type(4))) float f32x4;
typedef __attribute__((ext_vector_type(4))) unsigned short u16x4;

typedef __attribute__((address_space(3))) unsigned short lds_us;
typedef const __attribute__((address_space(1))) void glb_v;

static __device__ __forceinline__ unsigned short f2bfu(float f){
  __hip_bfloat16 h = __float2bfloat16(f);   // RNE
  unsigned short u;
  __builtin_memcpy(&u, &h, 2);
  return u;
}

static __device__ __forceinline__ f32x4 MFMA16(s16x8 a, s16x8 b, f32x4 c){
  return __builtin_amdgcn_mfma_f32_16x16x32_bf16(a, b, c, 0, 0, 0);
}

// ---------- fp32 -> bf16 elementwise ----------
__global__ __launch_bounds__(256) void cvt_bf16_kernel(const float* __restrict__ in,
                                                       unsigned short* __restrict__ out, int n4){
  int i = blockIdx.x*256 + threadIdx.x;
  if (i < n4){
    float4 v = reinterpret_cast<const float4*>(in)[i];
    u16x4 o;
    o.x = f2bfu(v.x); o.y = f2bfu(v.y); o.z = f2bfu(v.z); o.w = f2bfu(v.w);
    reinterpret_cast<u16x4*>(out)[i] = o;
  }
}

// ---------- fp32 [K][N] -> bf16 [N][K] (transpose + convert) ----------
__global__ __launch_bounds__(256) void transpose_cvt_kernel(const float* __restrict__ src,
                                                            unsigned short* __restrict__ dst,
                                                            int K, int N){
  __shared__ unsigned short tile[64][65];
  int n0 = blockIdx.x*64, k0 = blockIdx.y*64;
  int tid = threadIdx.x;
  #pragma unroll
  for (int i=0;i<16;i++){
    int e = i*256 + tid; int r = e>>6, c = e&63;
    tile[r][c] = f2bfu(src[(size_t)(k0+r)*N + n0 + c]);
  }
  __syncthreads();
  #pragma unroll
  for (int i=0;i<16;i++){
    int e = i*256 + tid; int r = e>>6, c = e&63;
    dst[(size_t)(n0+r)*K + k0 + c] = tile[c][r];
  }
}

// ---------- int32 mask -> bitmask [T][T/32] words ----------
__global__ __launch_bounds__(256) void mask_bits_kernel(const int* __restrict__ m,
                                                        unsigned int* __restrict__ bits){
  int i = blockIdx.x*256 + threadIdx.x;
  unsigned long long b = __ballot(m[i] == 1);
  int lane = threadIdx.x & 63;
  if (lane == 0)  bits[i>>5] = (unsigned int)b;
  if (lane == 32) bits[i>>5] = (unsigned int)(b>>32);
}

// ---------- v [BH][T][64] -> vT [BH][64][T] ----------
__global__ __launch_bounds__(256) void transpose_v_kernel(const unsigned short* __restrict__ v,
                                                          unsigned short* __restrict__ vt){
  __shared__ unsigned short tile[64][65];
  int bh = blockIdx.y;
  int t0 = blockIdx.x*64;
  const unsigned short* src = v + (size_t)bh*T_DIM*DHEAD;
  unsigned short* dst = vt + (size_t)bh*T_DIM*DHEAD;
  int tid = threadIdx.x;
  #pragma unroll
  for (int i=0;i<16;i++){
    int e = i*256+tid; int r = e>>6, c = e&63;
    tile[r][c] = src[(size_t)(t0+r)*DHEAD + c];
  }
  __syncthreads();
  #pragma unroll
  for (int i=0;i<16;i++){
    int e = i*256+tid; int r = e>>6, c = e&63;
    dst[(size_t)r*T_DIM + t0 + c] = tile[c][r];
  }
}

// ---------- GEMM: C[M][N] = A[M][K] @ Bt[N][K]^T + bias ----------
// m97-style: global_load_lds width-16 into linear [128][64] LDS with XOR-swizzle
// (rule 21: linear dest + inverse-swizzled SOURCE + swizzled READ; XOR is its own inverse).
// MODE 0: M=4096,N=3072 -> scatter q/k/v bf16 [B][H][T][64]
// MODE 1: M=4096,N=1024 -> fp32 out [M][N]
template<int MODE>
__global__ __launch_bounds__(256) void gemm_kernel(const unsigned short* __restrict__ A,
    const unsigned short* __restrict__ Bt, const float* __restrict__ bias,
    unsigned short* __restrict__ qo, unsigned short* __restrict__ ko,
    unsigned short* __restrict__ vo, float* __restrict__ out)
{
  const int K = 1024;
  __shared__ __align__(16) unsigned short As[128*64];
  __shared__ __align__(16) unsigned short Bs[128*64];
  int tid = threadIdx.x;
  int lane = tid & 63, wave = tid >> 6;
  int m0 = blockIdx.y*128, n0 = blockIdx.x*128;
  int wm = (wave>>1)*64, wn = (wave&1)*64;
  int lr = lane & 15, lg = lane >> 4;
  // staging geometry: issue i covers rows i*32 + wave*8 + (lane>>3), slot lane&7 (16B units)
  int srow  = wave*8 + (lane>>3);
  int sslot = (lane&7) ^ (lane>>3);           // pre-swizzled global slot
  const unsigned short* Asrc = A  + (size_t)(m0+srow)*K + sslot*8;
  const unsigned short* Bsrc = Bt + (size_t)(n0+srow)*K + sslot*8;
  unsigned ldsoff = (unsigned)(wave*512 + lane*8);   // elems; +i*2048 per issue
  f32x4 acc[4][4];
  #pragma unroll
  for (int i=0;i<4;i++){
    #pragma unroll
    for (int j=0;j<4;j++){
      #pragma unroll
      for (int r=0;r<4;r++) acc[i][j][r] = 0.f;
    }
  }
  for (int kt=0; kt<K; kt+=64){
    #pragma unroll
    for (int i=0;i<4;i++){
      __builtin_amdgcn_global_load_lds((glb_v*)(Asrc + (size_t)i*32*K + kt),
                                       (lds_us*)(As + ldsoff + i*2048), 16, 0, 0);
      __builtin_amdgcn_global_load_lds((glb_v*)(Bsrc + (size_t)i*32*K + kt),
                                       (lds_us*)(Bs + ldsoff + i*2048), 16, 0, 0);
    }
    __syncthreads();
    #pragma unroll
    for (int kk=0; kk<2; kk++){
      s16x8 av[4], bv[4];
      #pragma unroll
      for (int i=0;i<4;i++){
        av[i] = *reinterpret_cast<const s16x8*>(&As[(wm+i*16+lr)*64 + (((kk*4+lg)^(lr&7))<<3)]);
        bv[i] = *reinterpret_cast<const s16x8*>(&Bs[(wn+i*16+lr)*64 + (((kk*4+lg)^(lr&7))<<3)]);
      }
      #pragma unroll
      for (int i=0;i<4;i++){
        #pragma unroll
        for (int j=0;j<4;j++)
          acc[i][j] = MFMA16(av[i], bv[j], acc[i][j]);
      }
    }
    __syncthreads();
  }
  // epilogue: C row = m0+wm+i*16+lg*4+r, col = n0+wn+j*16+lr  (m89-verified C/D layout)
  #pragma unroll
  for (int j=0;j<4;j++){
    int n = n0 + wn + j*16 + lr;
    float bvl = bias[n];
    #pragma unroll
    for (int i=0;i<4;i++){
      #pragma unroll
      for (int r=0;r<4;r++){
        int m = m0 + wm + i*16 + lg*4 + r;
        float val = acc[i][j][r] + bvl;
        if (MODE == 0){
          int which = n >> 10, c = n & 1023;
          int h = c >> 6, d = c & 63;
          int b = m >> 11, t = m & 2047;
          size_t idx = ((size_t)((b*NHEAD + h)*T_DIM + t))*DHEAD + d;
          unsigned short us = f2bfu(val);
          if (which == 0) qo[idx] = us;
          else if (which == 1) ko[idx] = us;
          else vo[idx] = us;
        } else {
          out[(size_t)m*C_DIM + n] = val;
        }
      }
    }
  }
}

// ---------- flash attention: 4 waves x 16 q-rows, KV tiles of 64 ----------
// Swapped QK^T (lane owns q-row lr). K/V read DIRECT from global (L2/L1-resident:
// 512KB per head, shared by 4 waves x 32 q-blocks) -> no staging, no barriers.
// Softmax in log2 domain (exp2), scale folded.
__global__ __launch_bounds__(256) void attn_kernel(const unsigned short* __restrict__ q,
    const unsigned short* __restrict__ k, const unsigned short* __restrict__ vt,
    const unsigned int* __restrict__ mbits, unsigned short* __restrict__ aout)
{
  __shared__ __align__(16) unsigned short Ps[4][16][72];   // per-wave P tile [q=16][k=64+pad]
  int bh = blockIdx.y;
  int q0 = blockIdx.x*64;
  int tid = threadIdx.x, lane = tid&63, wave = tid>>6;
  int lr = lane&15, lg = lane>>4;
  const unsigned short* qp = q  + (size_t)bh*T_DIM*DHEAD;
  const unsigned short* kp = k  + (size_t)bh*T_DIM*DHEAD;
  const unsigned short* vp = vt + (size_t)bh*T_DIM*DHEAD;
  int qw = q0 + wave*16;
  s16x8 qf[2];
  #pragma unroll
  for (int kk=0;kk<2;kk++)
    qf[kk] = *reinterpret_cast<const s16x8*>(qp + (size_t)(qw+lr)*DHEAD + kk*32 + lg*8);
  f32x4 o[4];
  #pragma unroll
  for (int cb=0;cb<4;cb++){
    #pragma unroll
    for (int r=0;r<4;r++) o[cb][r]=0.f;
  }
  const float SC = 0.125f * 1.44269504f;   // 1/sqrt(dh) * log2(e): softmax in log2 domain
  float m = -1e30f, l = 0.f;               // m in log2 domain, for q-row (qw + lr)
  const unsigned int* mptr = mbits + (size_t)(qw + lr)*(T_DIM/32);

  for (int k0=0; k0<T_DIM; k0+=64){
    // S^T = K @ Q^T : st[cb] row = k_local = cb*16+lg*4+reg, col = q = lr
    f32x4 st[4];
    #pragma unroll
    for (int cb=0;cb<4;cb++){
      f32x4 a;
      #pragma unroll
      for (int r=0;r<4;r++) a[r]=0.f;
      #pragma unroll
      for (int kk=0;kk<2;kk++){
        s16x8 kf = *reinterpret_cast<const s16x8*>(
            kp + (size_t)(k0 + cb*16 + lr)*DHEAD + kk*32 + lg*8);
        a = MFMA16(kf, qf[kk], a);   // A=K rows, B=Q rows
      }
      st[cb] = a;
    }
    // scale + mask: lane's k's = k0 + 16cb + 4lg + reg -> 2 mask words per lane
    unsigned mw0 = mptr[(k0>>5)];
    unsigned mw1 = mptr[(k0>>5)+1];
    #pragma unroll
    for (int cb=0;cb<4;cb++){
      unsigned msel = (cb<2) ? mw0 : mw1;
      unsigned ms = msel >> ((cb&1)*16 + lg*4);
      #pragma unroll
      for (int r=0;r<4;r++){
        float val = st[cb][r]*SC;
        st[cb][r] = ((ms>>r)&1u) ? -1e30f : val;
      }
    }
    // online softmax (log2 domain): 16 in-lane + 2 cross-lg shuffles
    float pmax = st[0][0];
    #pragma unroll
    for (int cb=0;cb<4;cb++){
      #pragma unroll
      for (int r=0;r<4;r++) pmax = fmaxf(pmax, st[cb][r]);
    }
    pmax = fmaxf(pmax, __shfl_xor(pmax, 16));
    pmax = fmaxf(pmax, __shfl_xor(pmax, 32));
    float mnew = fmaxf(m, pmax);
    float corr = exp2f(m - mnew);
    m = mnew;
    float rs = 0.f;
    #pragma unroll
    for (int cb=0;cb<4;cb++){
      #pragma unroll
      for (int r=0;r<4;r++){
        float p = exp2f(st[cb][r] - mnew);
        st[cb][r] = p;
        rs += p;
      }
    }
    rs += __shfl_xor(rs, 16);
    rs += __shfl_xor(rs, 32);
    l = l*corr + rs;
    // rescale O (O rows are q = qw + lg*4 + r; fetch corr from the lane owning that row)
    float corrO[4];
    #pragma unroll
    for (int r=0;r<4;r++) corrO[r] = __shfl(corr, lg*4 + r);
    #pragma unroll
    for (int cb=0;cb<4;cb++){
      #pragma unroll
      for (int r=0;r<4;r++) o[cb][r] *= corrO[r];
    }
    // P^T lane-local: P[q=lr][k=16cb+4lg+reg], reg-consecutive k -> packed b64 writes
    #pragma unroll
    for (int cb=0;cb<4;cb++){
      s16x4 pk;
      #pragma unroll
      for (int r=0;r<4;r++) pk[r] = (short)f2bfu(st[cb][r]);
      *reinterpret_cast<s16x4*>(&Ps[wave][lr][cb*16 + lg*4]) = pk;
    }
    s16x8 pf[2];
    #pragma unroll
    for (int kk=0;kk<2;kk++)
      pf[kk] = *reinterpret_cast<const s16x8*>(&Ps[wave][lr][kk*32 + lg*8]);
    // O += P @ V   (B-fragment from vt rows d = cb*16+lr, direct global)
    #pragma unroll
    for (int cb=0;cb<4;cb++){
      #pragma unroll
      for (int kk=0;kk<2;kk++){
        s16x8 vf = *reinterpret_cast<const s16x8*>(
            vp + (size_t)(cb*16 + lr)*T_DIM + k0 + kk*32 + lg*8);
        o[cb] = MFMA16(pf[kk], vf, o[cb]);
      }
    }
  }
  int b = bh >> 4, h = bh & 15;
  float inv = l > 0.f ? 1.f/l : 0.f;       // for q-row lr
  #pragma unroll
  for (int r=0;r<4;r++){
    float invO = __shfl(inv, lg*4 + r);
    int row = b*T_DIM + qw + lg*4 + r;
    #pragma unroll
    for (int cb=0;cb<4;cb++){
      int d = cb*16 + lr;
      aout[(size_t)row*C_DIM + h*DHEAD + d] = f2bfu(o[cb][r]*invO);
    }
  }
}

extern "C" void kernel_launch(void* const* d_in, const int* in_sizes, int n_in,
                              void* d_out, int out_size, void* d_ws, size_t ws_size,
                              hipStream_t stream){
  const float* x     = (const float*)d_in[0];
  const int*   mask  = (const int*)d_in[1];
  const float* Wqkv  = (const float*)d_in[2];
  const float* bqkv  = (const float*)d_in[3];
  const float* Wproj = (const float*)d_in[4];
  const float* bproj = (const float*)d_in[5];
  float* out = (float*)d_out;
  char* ws = (char*)d_ws;
  const size_t MB = (size_t)1<<20;
  unsigned short* xb     = (unsigned short*)(ws + 0*MB);   // 8MB  x bf16 [4096][1024]; aliased as aout later
  unsigned short* wqkvT  = (unsigned short*)(ws + 8*MB);   // 6MB  [3072][1024]
  unsigned short* wprojT = (unsigned short*)(ws + 14*MB);  // 2MB  [1024][1024]
  unsigned int*   mbits  = (unsigned int*)(ws + 16*MB);    // 512KB [2048][64] words
  unsigned short* qb     = (unsigned short*)(ws + 17*MB);  // 8MB  [2][16][2048][64]
  unsigned short* kb     = (unsigned short*)(ws + 25*MB);  // 8MB
  unsigned short* vb     = (unsigned short*)(ws + 33*MB);  // 8MB
  unsigned short* vtb    = (unsigned short*)(ws + 41*MB);  // 8MB  [2][16][64][2048]  (uses 49MB total)
  unsigned short* aout   = xb;  // safe alias: xb only read by gemm<0>, attn runs after

  cvt_bf16_kernel<<<dim3(4096), dim3(256), 0, stream>>>(x, xb, (2*2048*1024)/4);
  transpose_cvt_kernel<<<dim3(48,16), dim3(256), 0, stream>>>(Wqkv, wqkvT, 1024, 3072);
  transpose_cvt_kernel<<<dim3(16,16), dim3(256), 0, stream>>>(Wproj, wprojT, 1024, 1024);
  mask_bits_kernel<<<dim3((2048*2048)/256), dim3(256), 0, stream>>>(mask, mbits);
  gemm_kernel<0><<<dim3(24,32), dim3(256), 0, stream>>>(xb, wqkvT, bqkv, qb, kb, vb, nullptr);
  transpose_v_kernel<<<dim3(32,32), dim3(256), 0, stream>>>(vb, vtb);
  attn_kernel<<<dim3(32,32), dim3(256), 0, stream>>>(qb, kb, vtb, mbits, aout);
  gemm_kernel<1><<<dim3(8,32), dim3(256), 0, stream>>>(aout, wprojT, bproj, nullptr, nullptr, nullptr, out);
}

// Round 8
// 258.573 us; speedup vs baseline: 1.5865x; 1.5865x over previous
//
#include <hip/hip_runtime.h>
#include <hip/hip_bf16.h>

#define T_DIM 2048
#define C_DIM 1024
#define NHEAD 16
#define DHEAD 64

typedef __attribute__((ext_vector_type(8))) short s16x8;   // 8 bf16 = 4 VGPRs
typedef __attribute__((ext_vector_type(4))) short s16x4;   // 4 bf16 = 2 VGPRs
typedef __attribute__((ext_vector_type(4))) float f32x4;
typedef __attribute__((ext_vector_type(4))) unsigned short u16x4;

typedef __attribute__((address_space(3))) unsigned short lds_us;
typedef const __attribute__((address_space(1))) void glb_v;

static __device__ __forceinline__ unsigned short f2bfu(float f){
  __hip_bfloat16 h = __float2bfloat16(f);   // RNE
  unsigned short u;
  __builtin_memcpy(&u, &h, 2);
  return u;
}

static __device__ __forceinline__ f32x4 MFMA16(s16x8 a, s16x8 b, f32x4 c){
  return __builtin_amdgcn_mfma_f32_16x16x32_bf16(a, b, c, 0, 0, 0);
}

// ---------- fp32 -> bf16 elementwise ----------
__global__ __launch_bounds__(256) void cvt_bf16_kernel(const float* __restrict__ in,
                                                       unsigned short* __restrict__ out, int n4){
  int i = blockIdx.x*256 + threadIdx.x;
  if (i < n4){
    float4 v = reinterpret_cast<const float4*>(in)[i];
    u16x4 o;
    o.x = f2bfu(v.x); o.y = f2bfu(v.y); o.z = f2bfu(v.z); o.w = f2bfu(v.w);
    reinterpret_cast<u16x4*>(out)[i] = o;
  }
}

// ---------- fp32 [K][N] -> bf16 [N][K] (transpose + convert) ----------
__global__ __launch_bounds__(256) void transpose_cvt_kernel(const float* __restrict__ src,
                                                            unsigned short* __restrict__ dst,
                                                            int K, int N){
  __shared__ unsigned short tile[64][65];
  int n0 = blockIdx.x*64, k0 = blockIdx.y*64;
  int tid = threadIdx.x;
  #pragma unroll
  for (int i=0;i<16;i++){
    int e = i*256 + tid; int r = e>>6, c = e&63;
    tile[r][c] = f2bfu(src[(size_t)(k0+r)*N + n0 + c]);
  }
  __syncthreads();
  #pragma unroll
  for (int i=0;i<16;i++){
    int e = i*256 + tid; int r = e>>6, c = e&63;
    dst[(size_t)(n0+r)*K + k0 + c] = tile[c][r];
  }
}

// ---------- int32 mask -> bitmask [T][T/32] words ----------
__global__ __launch_bounds__(256) void mask_bits_kernel(const int* __restrict__ m,
                                                        unsigned int* __restrict__ bits){
  int i = blockIdx.x*256 + threadIdx.x;
  unsigned long long b = __ballot(m[i] == 1);
  int lane = threadIdx.x & 63;
  if (lane == 0)  bits[i>>5] = (unsigned int)b;
  if (lane == 32) bits[i>>5] = (unsigned int)(b>>32);
}

// ---------- v [BH][T][64] -> vT [BH][64][T] ----------
__global__ __launch_bounds__(256) void transpose_v_kernel(const unsigned short* __restrict__ v,
                                                          unsigned short* __restrict__ vt){
  __shared__ unsigned short tile[64][65];
  int bh = blockIdx.y;
  int t0 = blockIdx.x*64;
  const unsigned short* src = v + (size_t)bh*T_DIM*DHEAD;
  unsigned short* dst = vt + (size_t)bh*T_DIM*DHEAD;
  int tid = threadIdx.x;
  #pragma unroll
  for (int i=0;i<16;i++){
    int e = i*256+tid; int r = e>>6, c = e&63;
    tile[r][c] = src[(size_t)(t0+r)*DHEAD + c];
  }
  __syncthreads();
  #pragma unroll
  for (int i=0;i<16;i++){
    int e = i*256+tid; int r = e>>6, c = e&63;
    dst[(size_t)r*T_DIM + t0 + c] = tile[c][r];
  }
}

// ---------- GEMM: C[M][N] = A[M][K] @ Bt[N][K]^T + bias ----------
// m97-style: global_load_lds width-16 into linear [128][64] LDS with XOR-swizzle
// (rule 21: linear dest + inverse-swizzled SOURCE + swizzled READ; XOR is its own inverse).
// Validated R7: absmax 1.95e-3 with this staging on both GEMMs.
// MODE 0: M=4096,N=3072 -> scatter q/k/v bf16 [B][H][T][64]
// MODE 1: M=4096,N=1024 -> fp32 out [M][N]
template<int MODE>
__global__ __launch_bounds__(256) void gemm_kernel(const unsigned short* __restrict__ A,
    const unsigned short* __restrict__ Bt, const float* __restrict__ bias,
    unsigned short* __restrict__ qo, unsigned short* __restrict__ ko,
    unsigned short* __restrict__ vo, float* __restrict__ out)
{
  const int K = 1024;
  __shared__ __align__(16) unsigned short As[128*64];
  __shared__ __align__(16) unsigned short Bs[128*64];
  int tid = threadIdx.x;
  int lane = tid & 63, wave = tid >> 6;
  int m0 = blockIdx.y*128, n0 = blockIdx.x*128;
  int wm = (wave>>1)*64, wn = (wave&1)*64;
  int lr = lane & 15, lg = lane >> 4;
  // staging geometry: issue i covers rows i*32 + wave*8 + (lane>>3), slot lane&7 (16B units)
  int srow  = wave*8 + (lane>>3);
  int sslot = (lane&7) ^ (lane>>3);           // pre-swizzled global slot
  const unsigned short* Asrc = A  + (size_t)(m0+srow)*K + sslot*8;
  const unsigned short* Bsrc = Bt + (size_t)(n0+srow)*K + sslot*8;
  unsigned ldsoff = (unsigned)(wave*512 + lane*8);   // elems; +i*2048 per issue
  f32x4 acc[4][4];
  #pragma unroll
  for (int i=0;i<4;i++){
    #pragma unroll
    for (int j=0;j<4;j++){
      #pragma unroll
      for (int r=0;r<4;r++) acc[i][j][r] = 0.f;
    }
  }
  for (int kt=0; kt<K; kt+=64){
    #pragma unroll
    for (int i=0;i<4;i++){
      __builtin_amdgcn_global_load_lds((glb_v*)(Asrc + (size_t)i*32*K + kt),
                                       (lds_us*)(As + ldsoff + i*2048), 16, 0, 0);
      __builtin_amdgcn_global_load_lds((glb_v*)(Bsrc + (size_t)i*32*K + kt),
                                       (lds_us*)(Bs + ldsoff + i*2048), 16, 0, 0);
    }
    __syncthreads();
    #pragma unroll
    for (int kk=0; kk<2; kk++){
      s16x8 av[4], bv[4];
      #pragma unroll
      for (int i=0;i<4;i++){
        av[i] = *reinterpret_cast<const s16x8*>(&As[(wm+i*16+lr)*64 + (((kk*4+lg)^(lr&7))<<3)]);
        bv[i] = *reinterpret_cast<const s16x8*>(&Bs[(wn+i*16+lr)*64 + (((kk*4+lg)^(lr&7))<<3)]);
      }
      #pragma unroll
      for (int i=0;i<4;i++){
        #pragma unroll
        for (int j=0;j<4;j++)
          acc[i][j] = MFMA16(av[i], bv[j], acc[i][j]);
      }
    }
    __syncthreads();
  }
  // epilogue: C row = m0+wm+i*16+lg*4+r, col = n0+wn+j*16+lr  (m89-verified C/D layout)
  #pragma unroll
  for (int j=0;j<4;j++){
    int n = n0 + wn + j*16 + lr;
    float bvl = bias[n];
    #pragma unroll
    for (int i=0;i<4;i++){
      #pragma unroll
      for (int r=0;r<4;r++){
        int m = m0 + wm + i*16 + lg*4 + r;
        float val = acc[i][j][r] + bvl;
        if (MODE == 0){
          int which = n >> 10, c = n & 1023;
          int h = c >> 6, d = c & 63;
          int b = m >> 11, t = m & 2047;
          size_t idx = ((size_t)((b*NHEAD + h)*T_DIM + t))*DHEAD + d;
          unsigned short us = f2bfu(val);
          if (which == 0) qo[idx] = us;
          else if (which == 1) ko[idx] = us;
          else vo[idx] = us;
        } else {
          out[(size_t)m*C_DIM + n] = val;
        }
      }
    }
  }
}

// ---------- flash attention: 4 waves x 16 q-rows, KV tiles of 64 ----------
// Swapped QK^T (lane owns q-row lr). K/V staged via global_load_lds width-16 into
// linear [64][64] LDS with the SAME validated XOR-swizzle involution as gemm_kernel
// (R7 lesson: direct-global fragment loads are 16-line scatters -> latency-bound 2.7x loss).
__global__ __launch_bounds__(256) void attn_kernel(const unsigned short* __restrict__ q,
    const unsigned short* __restrict__ k, const unsigned short* __restrict__ vt,
    const unsigned int* __restrict__ mbits, unsigned short* __restrict__ aout)
{
  __shared__ __align__(16) unsigned short Ks[64*64];
  __shared__ __align__(16) unsigned short Vs[64*64];       // vt rows d=0..63, cols k0..k0+63
  __shared__ __align__(16) unsigned short Ps[4][16][72];   // per-wave P tile [q=16][k=64+pad]
  int bh = blockIdx.y;
  int q0 = blockIdx.x*64;
  int tid = threadIdx.x, lane = tid&63, wave = tid>>6;
  int lr = lane&15, lg = lane>>4;
  const unsigned short* qp = q  + (size_t)bh*T_DIM*DHEAD;
  const unsigned short* kp = k  + (size_t)bh*T_DIM*DHEAD;
  const unsigned short* vp = vt + (size_t)bh*T_DIM*DHEAD;
  int qw = q0 + wave*16;
  s16x8 qf[2];
  #pragma unroll
  for (int kk=0;kk<2;kk++)
    qf[kk] = *reinterpret_cast<const s16x8*>(qp + (size_t)(qw+lr)*DHEAD + kk*32 + lg*8);
  // staging geometry (identical invariant to gemm: row&7 == lane>>3 for both issues)
  int srow  = wave*8 + (lane>>3);             // [0,32)
  int sslot = (lane&7) ^ (lane>>3);           // pre-swizzled global slot
  const unsigned short* Ksrc = kp + (size_t)srow*DHEAD + sslot*8;
  const unsigned short* Vsrc = vp + (size_t)srow*T_DIM + sslot*8;
  unsigned ldsoff = (unsigned)(wave*512 + lane*8);   // elems; +i*2048 per issue
  f32x4 o[4];
  #pragma unroll
  for (int cb=0;cb<4;cb++){
    #pragma unroll
    for (int r=0;r<4;r++) o[cb][r]=0.f;
  }
  const float SC = 0.125f * 1.44269504f;   // 1/sqrt(dh) * log2(e): softmax in log2 domain
  float m = -1e30f, l = 0.f;               // m in log2 domain, for q-row (qw + lr)
  const unsigned int* mptr = mbits + (size_t)(qw + lr)*(T_DIM/32);

  for (int k0=0; k0<T_DIM; k0+=64){
    #pragma unroll
    for (int i=0;i<2;i++){
      __builtin_amdgcn_global_load_lds((glb_v*)(Ksrc + (size_t)(k0 + i*32)*DHEAD),
                                       (lds_us*)(Ks + ldsoff + i*2048), 16, 0, 0);
      __builtin_amdgcn_global_load_lds((glb_v*)(Vsrc + (size_t)i*32*T_DIM + k0),
                                       (lds_us*)(Vs + ldsoff + i*2048), 16, 0, 0);
    }
    __syncthreads();
    // S^T = K @ Q^T : st[cb] row = k_local = cb*16+lg*4+reg, col = q = lr
    f32x4 st[4];
    #pragma unroll
    for (int cb=0;cb<4;cb++){
      f32x4 a;
      #pragma unroll
      for (int r=0;r<4;r++) a[r]=0.f;
      #pragma unroll
      for (int kk=0;kk<2;kk++){
        s16x8 kf = *reinterpret_cast<const s16x8*>(
            &Ks[(cb*16+lr)*64 + (((kk*4+lg)^(lr&7))<<3)]);
        a = MFMA16(kf, qf[kk], a);   // A=K rows, B=Q rows
      }
      st[cb] = a;
    }
    // scale + mask: lane's k's = k0 + 16cb + 4lg + reg -> 2 mask words per lane
    unsigned mw0 = mptr[(k0>>5)];
    unsigned mw1 = mptr[(k0>>5)+1];
    #pragma unroll
    for (int cb=0;cb<4;cb++){
      unsigned msel = (cb<2) ? mw0 : mw1;
      unsigned ms = msel >> ((cb&1)*16 + lg*4);
      #pragma unroll
      for (int r=0;r<4;r++){
        float val = st[cb][r]*SC;
        st[cb][r] = ((ms>>r)&1u) ? -1e30f : val;
      }
    }
    // online softmax (log2 domain): 16 in-lane + 2 cross-lg shuffles
    float pmax = st[0][0];
    #pragma unroll
    for (int cb=0;cb<4;cb++){
      #pragma unroll
      for (int r=0;r<4;r++) pmax = fmaxf(pmax, st[cb][r]);
    }
    pmax = fmaxf(pmax, __shfl_xor(pmax, 16));
    pmax = fmaxf(pmax, __shfl_xor(pmax, 32));
    float mnew = fmaxf(m, pmax);
    float corr = exp2f(m - mnew);
    m = mnew;
    float rs = 0.f;
    #pragma unroll
    for (int cb=0;cb<4;cb++){
      #pragma unroll
      for (int r=0;r<4;r++){
        float p = exp2f(st[cb][r] - mnew);
        st[cb][r] = p;
        rs += p;
      }
    }
    rs += __shfl_xor(rs, 16);
    rs += __shfl_xor(rs, 32);
    l = l*corr + rs;
    // rescale O (O rows are q = qw + lg*4 + r; fetch corr from the lane owning that row)
    float corrO[4];
    #pragma unroll
    for (int r=0;r<4;r++) corrO[r] = __shfl(corr, lg*4 + r);
    #pragma unroll
    for (int cb=0;cb<4;cb++){
      #pragma unroll
      for (int r=0;r<4;r++) o[cb][r] *= corrO[r];
    }
    // P^T lane-local: P[q=lr][k=16cb+4lg+reg], reg-consecutive k -> packed b64 writes
    #pragma unroll
    for (int cb=0;cb<4;cb++){
      s16x4 pk;
      #pragma unroll
      for (int r=0;r<4;r++) pk[r] = (short)f2bfu(st[cb][r]);
      *reinterpret_cast<s16x4*>(&Ps[wave][lr][cb*16 + lg*4]) = pk;
    }
    s16x8 pf[2];
    #pragma unroll
    for (int kk=0;kk<2;kk++)
      pf[kk] = *reinterpret_cast<const s16x8*>(&Ps[wave][lr][kk*32 + lg*8]);
    // O += P @ V   (B-fragment from Vs rows d = cb*16+lr, swizzled read)
    #pragma unroll
    for (int cb=0;cb<4;cb++){
      #pragma unroll
      for (int kk=0;kk<2;kk++){
        s16x8 vf = *reinterpret_cast<const s16x8*>(
            &Vs[(cb*16+lr)*64 + (((kk*4+lg)^(lr&7))<<3)]);
        o[cb] = MFMA16(pf[kk], vf, o[cb]);
      }
    }
    __syncthreads();   // protect Ks/Vs before next tile's DMA
  }
  int b = bh >> 4, h = bh & 15;
  float inv = l > 0.f ? 1.f/l : 0.f;       // for q-row lr
  #pragma unroll
  for (int r=0;r<4;r++){
    float invO = __shfl(inv, lg*4 + r);
    int row = b*T_DIM + qw + lg*4 + r;
    #pragma unroll
    for (int cb=0;cb<4;cb++){
      int d = cb*16 + lr;
      aout[(size_t)row*C_DIM + h*DHEAD + d] = f2bfu(o[cb][r]*invO);
    }
  }
}

extern "C" void kernel_launch(void* const* d_in, const int* in_sizes, int n_in,
                              void* d_out, int out_size, void* d_ws, size_t ws_size,
                              hipStream_t stream){
  const float* x     = (const float*)d_in[0];
  const int*   mask  = (const int*)d_in[1];
  const float* Wqkv  = (const float*)d_in[2];
  const float* bqkv  = (const float*)d_in[3];
  const float* Wproj = (const float*)d_in[4];
  const float* bproj = (const float*)d_in[5];
  float* out = (float*)d_out;
  char* ws = (char*)d_ws;
  const size_t MB = (size_t)1<<20;
  unsigned short* xb     = (unsigned short*)(ws + 0*MB);   // 8MB  x bf16 [4096][1024]; aliased as aout later
  unsigned short* wqkvT  = (unsigned short*)(ws + 8*MB);   // 6MB  [3072][1024]
  unsigned short* wprojT = (unsigned short*)(ws + 14*MB);  // 2MB  [1024][1024]
  unsigned int*   mbits  = (unsigned int*)(ws + 16*MB);    // 512KB [2048][64] words
  unsigned short* qb     = (unsigned short*)(ws + 17*MB);  // 8MB  [2][16][2048][64]
  unsigned short* kb     = (unsigned short*)(ws + 25*MB);  // 8MB
  unsigned short* vb     = (unsigned short*)(ws + 33*MB);  // 8MB
  unsigned short* vtb    = (unsigned short*)(ws + 41*MB);  // 8MB  [2][16][64][2048]  (uses 49MB total)
  unsigned short* aout   = xb;  // safe alias: xb only read by gemm<0>, attn runs after

  cvt_bf16_kernel<<<dim3(4096), dim3(256), 0, stream>>>(x, xb, (2*2048*1024)/4);
  transpose_cvt_kernel<<<dim3(48,16), dim3(256), 0, stream>>>(Wqkv, wqkvT, 1024, 3072);
  transpose_cvt_kernel<<<dim3(16,16), dim3(256), 0, stream>>>(Wproj, wprojT, 1024, 1024);
  mask_bits_kernel<<<dim3((2048*2048)/256), dim3(256), 0, stream>>>(mask, mbits);
  gemm_kernel<0><<<dim3(24,32), dim3(256), 0, stream>>>(xb, wqkvT, bqkv, qb, kb, vb, nullptr);
  transpose_v_kernel<<<dim3(32,32), dim3(256), 0, stream>>>(vb, vtb);
  attn_kernel<<<dim3(32,32), dim3(256), 0, stream>>>(qb, kb, vtb, mbits, aout);
  gemm_kernel<1><<<dim3(8,32), dim3(256), 0, stream>>>(aout, wprojT, bproj, nullptr, nullptr, nullptr, out);
}

// Round 9
// 253.976 us; speedup vs baseline: 1.6152x; 1.0181x over previous
//
#include <hip/hip_runtime.h>
#include <hip/hip_bf16.h>

#define T_DIM 2048
#define C_DIM 1024
#define NHEAD 16
#define DHEAD 64

typedef __attribute__((ext_vector_type(8))) short s16x8;   // 8 bf16 = 4 VGPRs
typedef __attribute__((ext_vector_type(4))) short s16x4;   // 4 bf16 = 2 VGPRs
typedef __attribute__((ext_vector_type(4))) float f32x4;
typedef __attribute__((ext_vector_type(4))) unsigned short u16x4;

typedef __attribute__((address_space(3))) unsigned short lds_us;
typedef const __attribute__((address_space(1))) void glb_v;

#define SC_QK (0.125f * 1.44269504f)   // 1/sqrt(dh) * log2(e), folded into Q at gemm<0> epilogue

static __device__ __forceinline__ unsigned short f2bfu(float f){
  __hip_bfloat16 h = __float2bfloat16(f);   // RNE
  unsigned short u;
  __builtin_memcpy(&u, &h, 2);
  return u;
}

static __device__ __forceinline__ unsigned cvt_pk_bf16(float lo, float hi){
  unsigned r;
  asm("v_cvt_pk_bf16_f32 %0, %1, %2" : "=v"(r) : "v"(lo), "v"(hi));
  return r;
}

static __device__ __forceinline__ f32x4 MFMA16(s16x8 a, s16x8 b, f32x4 c){
  return __builtin_amdgcn_mfma_f32_16x16x32_bf16(a, b, c, 0, 0, 0);
}

// ---------- fp32 -> bf16 elementwise ----------
__global__ __launch_bounds__(256) void cvt_bf16_kernel(const float* __restrict__ in,
                                                       unsigned short* __restrict__ out, int n4){
  int i = blockIdx.x*256 + threadIdx.x;
  if (i < n4){
    float4 v = reinterpret_cast<const float4*>(in)[i];
    u16x4 o;
    o.x = f2bfu(v.x); o.y = f2bfu(v.y); o.z = f2bfu(v.z); o.w = f2bfu(v.w);
    reinterpret_cast<u16x4*>(out)[i] = o;
  }
}

// ---------- fp32 [K][N] -> bf16 [N][K] (transpose + convert) ----------
__global__ __launch_bounds__(256) void transpose_cvt_kernel(const float* __restrict__ src,
                                                            unsigned short* __restrict__ dst,
                                                            int K, int N){
  __shared__ unsigned short tile[64][65];
  int n0 = blockIdx.x*64, k0 = blockIdx.y*64;
  int tid = threadIdx.x;
  #pragma unroll
  for (int i=0;i<16;i++){
    int e = i*256 + tid; int r = e>>6, c = e&63;
    tile[r][c] = f2bfu(src[(size_t)(k0+r)*N + n0 + c]);
  }
  __syncthreads();
  #pragma unroll
  for (int i=0;i<16;i++){
    int e = i*256 + tid; int r = e>>6, c = e&63;
    dst[(size_t)(n0+r)*K + k0 + c] = tile[c][r];
  }
}

// ---------- int32 mask -> bitmask [T][T/32] words ----------
__global__ __launch_bounds__(256) void mask_bits_kernel(const int* __restrict__ m,
                                                        unsigned int* __restrict__ bits){
  int i = blockIdx.x*256 + threadIdx.x;
  unsigned long long b = __ballot(m[i] == 1);
  int lane = threadIdx.x & 63;
  if (lane == 0)  bits[i>>5] = (unsigned int)b;
  if (lane == 32) bits[i>>5] = (unsigned int)(b>>32);
}

// ---------- v [BH][T][64] -> vT [BH][64][T] ----------
__global__ __launch_bounds__(256) void transpose_v_kernel(const unsigned short* __restrict__ v,
                                                          unsigned short* __restrict__ vt){
  __shared__ unsigned short tile[64][65];
  int bh = blockIdx.y;
  int t0 = blockIdx.x*64;
  const unsigned short* src = v + (size_t)bh*T_DIM*DHEAD;
  unsigned short* dst = vt + (size_t)bh*T_DIM*DHEAD;
  int tid = threadIdx.x;
  #pragma unroll
  for (int i=0;i<16;i++){
    int e = i*256+tid; int r = e>>6, c = e&63;
    tile[r][c] = src[(size_t)(t0+r)*DHEAD + c];
  }
  __syncthreads();
  #pragma unroll
  for (int i=0;i<16;i++){
    int e = i*256+tid; int r = e>>6, c = e&63;
    dst[(size_t)r*T_DIM + t0 + c] = tile[c][r];
  }
}

// ---------- GEMM: C[M][N] = A[M][K] @ Bt[N][K]^T + bias ----------
// global_load_lds width-16 into linear [128][64] LDS with XOR-swizzle (validated R7).
// MODE 0: M=4096,N=3072 -> scatter q/k/v bf16 [B][H][T][64]; Q pre-scaled by SC_QK
// MODE 1: M=4096,N=1024 -> fp32 out [M][N]
template<int MODE>
__global__ __launch_bounds__(256) void gemm_kernel(const unsigned short* __restrict__ A,
    const unsigned short* __restrict__ Bt, const float* __restrict__ bias,
    unsigned short* __restrict__ qo, unsigned short* __restrict__ ko,
    unsigned short* __restrict__ vo, float* __restrict__ out)
{
  const int K = 1024;
  __shared__ __align__(16) unsigned short As[128*64];
  __shared__ __align__(16) unsigned short Bs[128*64];
  int tid = threadIdx.x;
  int lane = tid & 63, wave = tid >> 6;
  int m0 = blockIdx.y*128, n0 = blockIdx.x*128;
  int wm = (wave>>1)*64, wn = (wave&1)*64;
  int lr = lane & 15, lg = lane >> 4;
  // staging geometry: issue i covers rows i*32 + wave*8 + (lane>>3), slot lane&7 (16B units)
  int srow  = wave*8 + (lane>>3);
  int sslot = (lane&7) ^ (lane>>3);           // pre-swizzled global slot
  const unsigned short* Asrc = A  + (size_t)(m0+srow)*K + sslot*8;
  const unsigned short* Bsrc = Bt + (size_t)(n0+srow)*K + sslot*8;
  unsigned ldsoff = (unsigned)(wave*512 + lane*8);   // elems; +i*2048 per issue
  f32x4 acc[4][4];
  #pragma unroll
  for (int i=0;i<4;i++){
    #pragma unroll
    for (int j=0;j<4;j++){
      #pragma unroll
      for (int r=0;r<4;r++) acc[i][j][r] = 0.f;
    }
  }
  for (int kt=0; kt<K; kt+=64){
    #pragma unroll
    for (int i=0;i<4;i++){
      __builtin_amdgcn_global_load_lds((glb_v*)(Asrc + (size_t)i*32*K + kt),
                                       (lds_us*)(As + ldsoff + i*2048), 16, 0, 0);
      __builtin_amdgcn_global_load_lds((glb_v*)(Bsrc + (size_t)i*32*K + kt),
                                       (lds_us*)(Bs + ldsoff + i*2048), 16, 0, 0);
    }
    __syncthreads();
    #pragma unroll
    for (int kk=0; kk<2; kk++){
      s16x8 av[4], bv[4];
      #pragma unroll
      for (int i=0;i<4;i++){
        av[i] = *reinterpret_cast<const s16x8*>(&As[(wm+i*16+lr)*64 + (((kk*4+lg)^(lr&7))<<3)]);
        bv[i] = *reinterpret_cast<const s16x8*>(&Bs[(wn+i*16+lr)*64 + (((kk*4+lg)^(lr&7))<<3)]);
      }
      #pragma unroll
      for (int i=0;i<4;i++){
        #pragma unroll
        for (int j=0;j<4;j++)
          acc[i][j] = MFMA16(av[i], bv[j], acc[i][j]);
      }
    }
    __syncthreads();
  }
  // epilogue: C row = m0+wm+i*16+lg*4+r, col = n0+wn+j*16+lr  (m89-verified C/D layout)
  #pragma unroll
  for (int j=0;j<4;j++){
    int n = n0 + wn + j*16 + lr;
    float bvl = bias[n];
    #pragma unroll
    for (int i=0;i<4;i++){
      #pragma unroll
      for (int r=0;r<4;r++){
        int m = m0 + wm + i*16 + lg*4 + r;
        float val = acc[i][j][r] + bvl;
        if (MODE == 0){
          int which = n >> 10, c = n & 1023;
          int h = c >> 6, d = c & 63;
          int b = m >> 11, t = m & 2047;
          size_t idx = ((size_t)((b*NHEAD + h)*T_DIM + t))*DHEAD + d;
          if (which == 0)      qo[idx] = f2bfu(val * SC_QK);  // fold softmax scale into Q (fp32 mul, single round)
          else if (which == 1) ko[idx] = f2bfu(val);
          else                 vo[idx] = f2bfu(val);
        } else {
          out[(size_t)m*C_DIM + n] = val;
        }
      }
    }
  }
}

// ---------- flash attention: 4 waves x 16 q-rows, KV tiles of 64 ----------
// Swapped QK^T (lane owns q-row lr), DMA-staged K/V (validated R8).
// R9 VALU-reduction bundle: scale pre-folded into Q; l accumulated via MFMA
// ones-column (o[4], same lane layout as o -> shuffle-free epilogue);
// cvt_pk_bf16 packing; defer-max rescale skip (THR=8, wave-uniform).
__global__ __launch_bounds__(256) void attn_kernel(const unsigned short* __restrict__ q,
    const unsigned short* __restrict__ k, const unsigned short* __restrict__ vt,
    const unsigned int* __restrict__ mbits, unsigned short* __restrict__ aout)
{
  __shared__ __align__(16) unsigned short Ks[64*64];
  __shared__ __align__(16) unsigned short Vs[64*64];       // vt rows d=0..63, cols k0..k0+63
  __shared__ __align__(16) unsigned short Ps[4][16][72];   // per-wave P tile [q=16][k=64+pad]
  int bh = blockIdx.y;
  int q0 = blockIdx.x*64;
  int tid = threadIdx.x, lane = tid&63, wave = tid>>6;
  int lr = lane&15, lg = lane>>4;
  const unsigned short* qp = q  + (size_t)bh*T_DIM*DHEAD;
  const unsigned short* kp = k  + (size_t)bh*T_DIM*DHEAD;
  const unsigned short* vp = vt + (size_t)bh*T_DIM*DHEAD;
  int qw = q0 + wave*16;
  s16x8 qf[2];
  #pragma unroll
  for (int kk=0;kk<2;kk++)
    qf[kk] = *reinterpret_cast<const s16x8*>(qp + (size_t)(qw+lr)*DHEAD + kk*32 + lg*8);
  s16x8 ones;
  #pragma unroll
  for (int j=0;j<8;j++) ones[j] = (short)0x3F80;   // bf16 1.0
  // staging geometry (row&7 == lane>>3 invariant, same involution as gemm)
  int srow  = wave*8 + (lane>>3);             // [0,32)
  int sslot = (lane&7) ^ (lane>>3);           // pre-swizzled global slot
  const unsigned short* Ksrc = kp + (size_t)srow*DHEAD + sslot*8;
  const unsigned short* Vsrc = vp + (size_t)srow*T_DIM + sslot*8;
  unsigned ldsoff = (unsigned)(wave*512 + lane*8);   // elems; +i*2048 per issue
  f32x4 o[5];   // o[0..3] = O columns, o[4] = row-sum (l) via ones-MFMA
  #pragma unroll
  for (int cb=0;cb<5;cb++){
    #pragma unroll
    for (int r=0;r<4;r++) o[cb][r]=0.f;
  }
  float m = -1e30f;                        // running max (log2 domain), q-row (qw + lr)
  const unsigned int* mptr = mbits + (size_t)(qw + lr)*(T_DIM/32);

  for (int k0=0; k0<T_DIM; k0+=64){
    #pragma unroll
    for (int i=0;i<2;i++){
      __builtin_amdgcn_global_load_lds((glb_v*)(Ksrc + (size_t)(k0 + i*32)*DHEAD),
                                       (lds_us*)(Ks + ldsoff + i*2048), 16, 0, 0);
      __builtin_amdgcn_global_load_lds((glb_v*)(Vsrc + (size_t)i*32*T_DIM + k0),
                                       (lds_us*)(Vs + ldsoff + i*2048), 16, 0, 0);
    }
    __syncthreads();
    // S^T = K @ Q^T (Q pre-scaled): st[cb] row = k_local = cb*16+lg*4+reg, col = q = lr
    f32x4 st[4];
    #pragma unroll
    for (int cb=0;cb<4;cb++){
      f32x4 a;
      #pragma unroll
      for (int r=0;r<4;r++) a[r]=0.f;
      #pragma unroll
      for (int kk=0;kk<2;kk++){
        s16x8 kf = *reinterpret_cast<const s16x8*>(
            &Ks[(cb*16+lr)*64 + (((kk*4+lg)^(lr&7))<<3)]);
        a = MFMA16(kf, qf[kk], a);   // A=K rows, B=Q rows
      }
      st[cb] = a;
    }
    // mask only (scale already folded): lane's k's = k0 + 16cb + 4lg + reg
    unsigned mw0 = mptr[(k0>>5)];
    unsigned mw1 = mptr[(k0>>5)+1];
    #pragma unroll
    for (int cb=0;cb<4;cb++){
      unsigned msel = (cb<2) ? mw0 : mw1;
      unsigned ms = msel >> ((cb&1)*16 + lg*4);
      #pragma unroll
      for (int r=0;r<4;r++)
        st[cb][r] = ((ms>>r)&1u) ? -1e30f : st[cb][r];
    }
    // row max: 15 in-lane + 2 cross-lg shuffles
    float pmax = st[0][0];
    #pragma unroll
    for (int cb=0;cb<4;cb++){
      #pragma unroll
      for (int r=0;r<4;r++) pmax = fmaxf(pmax, st[cb][r]);
    }
    pmax = fmaxf(pmax, __shfl_xor(pmax, 16));
    pmax = fmaxf(pmax, __shfl_xor(pmax, 32));
    // defer-max: skip rescale while tile max stays within 2^8 of running max
    if (!__all(pmax <= m + 8.0f)){
      float mnew = fmaxf(m, pmax);
      float corr = exp2f(m - mnew);
      m = mnew;
      float corrO[4];
      #pragma unroll
      for (int r=0;r<4;r++) corrO[r] = __shfl(corr, lg*4 + r);
      #pragma unroll
      for (int cb=0;cb<5;cb++){
        #pragma unroll
        for (int r=0;r<4;r++) o[cb][r] *= corrO[r];
      }
    }
    // P = exp2(st - m)  (bounded by 2^8 under defer)
    #pragma unroll
    for (int cb=0;cb<4;cb++){
      #pragma unroll
      for (int r=0;r<4;r++) st[cb][r] = exp2f(st[cb][r] - m);
    }
    // P^T lane-local -> Ps via packed cvt_pk (k pairs are reg-consecutive)
    #pragma unroll
    for (int cb=0;cb<4;cb++){
      uint2 w;
      w.x = cvt_pk_bf16(st[cb][0], st[cb][1]);
      w.y = cvt_pk_bf16(st[cb][2], st[cb][3]);
      *reinterpret_cast<uint2*>(&Ps[wave][lr][cb*16 + lg*4]) = w;
    }
    s16x8 pf[2];
    #pragma unroll
    for (int kk=0;kk<2;kk++)
      pf[kk] = *reinterpret_cast<const s16x8*>(&Ps[wave][lr][kk*32 + lg*8]);
    // O += P @ V ; l (o[4]) += P @ 1
    #pragma unroll
    for (int cb=0;cb<4;cb++){
      #pragma unroll
      for (int kk=0;kk<2;kk++){
        s16x8 vf = *reinterpret_cast<const s16x8*>(
            &Vs[(cb*16+lr)*64 + (((kk*4+lg)^(lr&7))<<3)]);
        o[cb] = MFMA16(pf[kk], vf, o[cb]);
      }
    }
    o[4] = MFMA16(pf[0], ones, o[4]);
    o[4] = MFMA16(pf[1], ones, o[4]);
    __syncthreads();   // protect Ks/Vs before next tile's DMA
  }
  int b = bh >> 4, h = bh & 15;
  #pragma unroll
  for (int r=0;r<4;r++){
    float l = o[4][r];                      // row-sum for q = qw + lg*4 + r (same layout as o)
    float invO = l > 0.f ? 1.f/l : 0.f;
    int row = b*T_DIM + qw + lg*4 + r;
    #pragma unroll
    for (int cb=0;cb<4;cb++){
      int d = cb*16 + lr;
      aout[(size_t)row*C_DIM + h*DHEAD + d] = f2bfu(o[cb][r]*invO);
    }
  }
}

extern "C" void kernel_launch(void* const* d_in, const int* in_sizes, int n_in,
                              void* d_out, int out_size, void* d_ws, size_t ws_size,
                              hipStream_t stream){
  const float* x     = (const float*)d_in[0];
  const int*   mask  = (const int*)d_in[1];
  const float* Wqkv  = (const float*)d_in[2];
  const float* bqkv  = (const float*)d_in[3];
  const float* Wproj = (const float*)d_in[4];
  const float* bproj = (const float*)d_in[5];
  float* out = (float*)d_out;
  char* ws = (char*)d_ws;
  const size_t MB = (size_t)1<<20;
  unsigned short* xb     = (unsigned short*)(ws + 0*MB);   // 8MB  x bf16 [4096][1024]; aliased as aout later
  unsigned short* wqkvT  = (unsigned short*)(ws + 8*MB);   // 6MB  [3072][1024]
  unsigned short* wprojT = (unsigned short*)(ws + 14*MB);  // 2MB  [1024][1024]
  unsigned int*   mbits  = (unsigned int*)(ws + 16*MB);    // 512KB [2048][64] words
  unsigned short* qb     = (unsigned short*)(ws + 17*MB);  // 8MB  [2][16][2048][64]
  unsigned short* kb     = (unsigned short*)(ws + 25*MB);  // 8MB
  unsigned short* vb     = (unsigned short*)(ws + 33*MB);  // 8MB
  unsigned short* vtb    = (unsigned short*)(ws + 41*MB);  // 8MB  [2][16][64][2048]  (uses 49MB total)
  unsigned short* aout   = xb;  // safe alias: xb only read by gemm<0>, attn runs after

  cvt_bf16_kernel<<<dim3(4096), dim3(256), 0, stream>>>(x, xb, (2*2048*1024)/4);
  transpose_cvt_kernel<<<dim3(48,16), dim3(256), 0, stream>>>(Wqkv, wqkvT, 1024, 3072);
  transpose_cvt_kernel<<<dim3(16,16), dim3(256), 0, stream>>>(Wproj, wprojT, 1024, 1024);
  mask_bits_kernel<<<dim3((2048*2048)/256), dim3(256), 0, stream>>>(mask, mbits);
  gemm_kernel<0><<<dim3(24,32), dim3(256), 0, stream>>>(xb, wqkvT, bqkv, qb, kb, vb, nullptr);
  transpose_v_kernel<<<dim3(32,32), dim3(256), 0, stream>>>(vb, vtb);
  attn_kernel<<<dim3(32,32), dim3(256), 0, stream>>>(qb, kb, vtb, mbits, aout);
  gemm_kernel<1><<<dim3(8,32), dim3(256), 0, stream>>>(aout, wprojT, bproj, nullptr, nullptr, nullptr, out);
}